// Round 16
// baseline (196.363 us; speedup 1.0000x reference)
//
#include <hip/hip_runtime.h>

using s16x8 = __attribute__((ext_vector_type(8))) short;
using f32x4 = __attribute__((ext_vector_type(4))) float;
typedef unsigned int   u32;
typedef unsigned short u16;

__device__ __forceinline__ u16 f2bf(float f) {
  u32 u = __float_as_uint(f);
  u += 0x7fffu + ((u >> 16) & 1u);   // round-to-nearest-even
  return (u16)(u >> 16);
}
__device__ __forceinline__ float bf2f(u16 s) {
  return __uint_as_float(((u32)s) << 16);
}

typedef __attribute__((address_space(1))) const unsigned int g_u32;
typedef __attribute__((address_space(3))) unsigned int l_u32;
__device__ __forceinline__ void gload16(const void* g, void* l) {
  __builtin_amdgcn_global_load_lds((g_u32*)g, (l_u32*)l, 16, 0, 0);
}

// counted waitcnt + raw barrier (no compiler vmcnt(0) drain)
#define WAITB(N) asm volatile("s_waitcnt vmcnt(" #N ")\ns_barrier" ::: "memory")
#define BAR()    asm volatile("s_barrier" ::: "memory")

// K fragment-order address (u16 index): [bh][chunk][pair(n,h)][lane][8]
__device__ __forceinline__ size_t kfrag_addr(int bh, int t, int e) {
  const int pair = (((t >> 4) & 3) << 1) + (e >> 5);
  const int slot = ((e >> 3) & 3) * 16 + (t & 15);
  return ((((size_t)bh * 32 + (t >> 6)) * 8 + pair) * 64 + slot) * 8 + (e & 7);
}
// V fragment-order address: subtile n = e>>4, k-dim = token
__device__ __forceinline__ size_t vfrag_addr(int bh, int t, int e) {
  const int pair = (((e >> 4) & 3) << 1) + ((t >> 5) & 1);
  const int slot = ((t >> 3) & 3) * 16 + (e & 15);
  return ((((size_t)bh * 32 + (t >> 6)) * 8 + pair) * 64 + slot) * 8 + (t & 7);
}

// ---------------------------------------------------------------------------
// Tiled transpose+pack: src f32 [z][R][C] -> dst bf16 [z][C][R]. 64x64 tiles.
// ---------------------------------------------------------------------------
__global__ __launch_bounds__(256) void transpose_pack(
    const float* __restrict__ src, u16* __restrict__ dst, int R, int C)
{
  __shared__ u16 tile[64][66];
  const int tid = threadIdx.x;
  const int c0 = blockIdx.x * 64, r0 = blockIdx.y * 64;
  const size_t zoff = (size_t)blockIdx.z * R * C;
  src += zoff; dst += zoff;
  const int rr = tid >> 6, cc = tid & 63;
  #pragma unroll
  for (int i = 0; i < 16; ++i)
    tile[i * 4 + rr][cc] = f2bf(src[(size_t)(r0 + i * 4 + rr) * C + c0 + cc]);
  __syncthreads();
  #pragma unroll
  for (int i = 0; i < 16; ++i)
    dst[(size_t)(c0 + i * 4 + rr) * R + r0 + cc] = tile[cc][i * 4 + rr];
}

// Fused Wq/Wk/Wv transpose: z = matrix*16 + head; each head is [1024][64].
__global__ __launch_bounds__(256) void transpose_qkv(
    const float* __restrict__ Wq, const float* __restrict__ Wk,
    const float* __restrict__ Wv, u16* __restrict__ dst)
{
  __shared__ u16 tile[64][66];
  const int tid = threadIdx.x;
  const int sel = blockIdx.z >> 4, head = blockIdx.z & 15;
  const int r0 = blockIdx.y * 64;
  const float* src = ((sel == 0) ? Wq : (sel == 1) ? Wk : Wv) + (size_t)head * 65536;
  u16* d = dst + ((size_t)sel << 20) + (size_t)head * 65536;
  const int rr = tid >> 6, cc = tid & 63;
  #pragma unroll
  for (int i = 0; i < 16; ++i)
    tile[i * 4 + rr][cc] = f2bf(src[(size_t)(r0 + i * 4 + rr) * 64 + cc]);
  __syncthreads();
  #pragma unroll
  for (int i = 0; i < 16; ++i)
    d[(size_t)(i * 4 + rr) * 1024 + r0 + cc] = tile[cc][i * 4 + rr];
}

// ---------------------------------------------------------------------------
// LayerNorm: f32 [4096][1024] -> bf16 [4096][1024]. One block per row.
// ---------------------------------------------------------------------------
__global__ __launch_bounds__(256) void ln_kernel(
    const float* __restrict__ x, const float* __restrict__ g,
    const float* __restrict__ be, u16* __restrict__ out)
{
  const int row = blockIdx.x, tid = threadIdx.x;
  const int lane = tid & 63, wave = tid >> 6;
  const float4 v = ((const float4*)(x + (size_t)row * 1024))[tid];
  float s  = v.x + v.y + v.z + v.w;
  float sq = v.x * v.x + v.y * v.y + v.z * v.z + v.w * v.w;
  #pragma unroll
  for (int m = 1; m < 64; m <<= 1) { s += __shfl_xor(s, m); sq += __shfl_xor(sq, m); }
  __shared__ float rs[4], rq[4];
  if (lane == 0) { rs[wave] = s; rq[wave] = sq; }
  __syncthreads();
  s  = rs[0] + rs[1] + rs[2] + rs[3];
  sq = rq[0] + rq[1] + rq[2] + rq[3];
  const float mean = s * (1.0f / 1024.0f);
  const float var  = sq * (1.0f / 1024.0f) - mean * mean;
  const float rstd = rsqrtf(var + 1e-5f);
  const int c = tid * 4;
  const float4 gv = ((const float4*)g)[tid];
  const float4 bv = ((const float4*)be)[tid];
  ushort4 o;
  o.x = f2bf((v.x - mean) * rstd * gv.x + bv.x);
  o.y = f2bf((v.y - mean) * rstd * gv.y + bv.y);
  o.z = f2bf((v.z - mean) * rstd * gv.z + bv.z);
  o.w = f2bf((v.w - mean) * rstd * gv.w + bv.w);
  *(ushort4*)&out[(size_t)row * 1024 + c] = o;
}

// ---------------------------------------------------------------------------
// bf16 MFMA GEMM: C = A[M][K]*BT[N][K]^T. Tile (64*MR)x128, BK=32, 4 waves,
// depth-3 LDS ring, counted-vmcnt raw barrier, swizzled staging, XCD swizzle.
// MODE 0: QKV epilogue (q scaled LOG2E/32; K,V -> fragment-order layouts)
// ---------------------------------------------------------------------------
template<int MODE, int MR>
__global__ __launch_bounds__(256) void gemm128(
    const u16* __restrict__ A, const u16* __restrict__ BT, int K,
    u16* __restrict__ o0q, u16* __restrict__ o0k, u16* __restrict__ o0v,
    u16* __restrict__ o1, const float* __restrict__ bias,
    float* __restrict__ o2, const float* __restrict__ resid)
{
  constexpr int BM = 64 * MR;
  __shared__ alignas(16) u16 As[3][BM * 32];
  __shared__ alignas(16) u16 Bs[3][128 * 32];
  const int tid = threadIdx.x, lane = tid & 63, wave = tid >> 6;
  const int wr = wave >> 1, wc = wave & 1;
  const int gx = gridDim.x;
  const int nwg = gx * gridDim.y;
  int lid = blockIdx.y * gx + blockIdx.x;
  lid = (lid & 7) * (nwg >> 3) + (lid >> 3);
  const int row0 = (lid / gx) * BM, col0 = (lid % gx) * 128;
  const int fr = lane & 15, g = lane >> 4;
  const int swz = (g ^ ((fr >> 1) & 3)) * 8;

  const int sr = wave * 16 + (lane >> 2);
  const int sc = ((lane & 3) ^ ((lane >> 3) & 3)) * 8;
  const u16* Ap0 = A  + (size_t)(row0 + sr) * K + sc;
  const u16* Ap1 = A  + (size_t)(row0 + 64 + sr) * K + sc;
  const u16* Bp0 = BT + (size_t)(col0 + sr) * K + sc;
  const u16* Bp1 = BT + (size_t)(col0 + 64 + sr) * K + sc;

  f32x4 acc[2 * MR][4] = {};

  auto stage = [&](int sel, int k0) {
    gload16(Ap0 + k0, &As[sel][wave * 512]);
    if constexpr (MR == 2) gload16(Ap1 + k0, &As[sel][(4 + wave) * 512]);
    gload16(Bp0 + k0, &Bs[sel][wave * 512]);
    gload16(Bp1 + k0, &Bs[sel][(4 + wave) * 512]);
  };
  auto compute = [&](int sel) {
    s16x8 af[2 * MR], bfr[4];
    #pragma unroll
    for (int m = 0; m < 2 * MR; ++m)
      af[m] = *(const s16x8*)&As[sel][(wr * (32 * MR) + m * 16 + fr) * 32 + swz];
    #pragma unroll
    for (int n = 0; n < 4; ++n)
      bfr[n] = *(const s16x8*)&Bs[sel][(wc * 64 + n * 16 + fr) * 32 + swz];
    #pragma unroll
    for (int m = 0; m < 2 * MR; ++m)
      #pragma unroll
      for (int n = 0; n < 4; ++n)
        acc[m][n] = __builtin_amdgcn_mfma_f32_16x16x32_bf16(af[m], bfr[n], acc[m][n], 0, 0, 0);
  };

  const int nsteps = K / 32;
  stage(0, 0);
  stage(1, 32);
  int cur = 0;
  for (int t = 0; t < nsteps - 1; ++t) {
    if constexpr (MR == 2) WAITB(4); else WAITB(3);
    const int nxt = (cur == 2) ? 0 : cur + 1;
    const int nn  = (nxt == 2) ? 0 : nxt + 1;
    if (t + 2 < nsteps) stage(nn, (t + 2) * 32);
    compute(cur);
    cur = nxt;
  }
  WAITB(0);
  compute(cur);

  const float QSCALE = 0.03125f * 1.4426950408889634f;  // d^-0.5 * log2(e)
  #pragma unroll
  for (int m = 0; m < 2 * MR; ++m) {
    const int rbase = row0 + wr * (32 * MR) + m * 16 + g * 4;
    #pragma unroll
    for (int n = 0; n < 4; ++n) {
      const int col = col0 + wc * 64 + n * 16 + fr;
      if constexpr (MODE == 0) {
        const int ww = col >> 10, h = (col >> 6) & 15, e = col & 63;
        const int b = rbase >> 11, t0 = rbase & 2047;
        const int bh = b * 16 + h;
        if (ww == 0) {
          #pragma unroll
          for (int j = 0; j < 4; ++j)
            o0q[((size_t)bh * 2048 + (t0 + j)) * 64 + e] = f2bf(acc[m][n][j] * QSCALE);
        } else if (ww == 1) {
          #pragma unroll
          for (int j = 0; j < 4; ++j)
            o0k[kfrag_addr(bh, t0 + j, e)] = f2bf(acc[m][n][j]);
        } else {
          ushort4 pk;
          pk.x = f2bf(acc[m][n][0]); pk.y = f2bf(acc[m][n][1]);
          pk.z = f2bf(acc[m][n][2]); pk.w = f2bf(acc[m][n][3]);
          *(ushort4*)&o0v[vfrag_addr(bh, t0, e)] = pk;
        }
      } else if constexpr (MODE == 1) {
        const float bb = bias[col];
        #pragma unroll
        for (int j = 0; j < 4; ++j) {
          float v = fmaxf(acc[m][n][j] + bb, 0.0f);
          o1[(size_t)(rbase + j) * 4096 + col] = f2bf(v);
        }
      } else {
        const float bb = bias[col];
        #pragma unroll
        for (int j = 0; j < 4; ++j) {
          const size_t ix = (size_t)(rbase + j) * 1024 + col;
          o2[ix] = acc[m][n][j] + bb + resid[ix];
        }
      }
    }
  }
}

// ---------------------------------------------------------------------------
// 8-phase 256x256 GEMM (m201-style). BK=64, 512 thr, 8 waves (2M x 4N),
// per-wave 128x64 out, 128KB LDS double-buffer, involution swizzle,
// raw barriers, vmcnt(6) at K-tile boundaries only, setprio, XCD swizzle.
// MODE 1: +bias+ReLU -> bf16 [.][4096]
// MODE 3: raw bf16 partial [.][1024] (split-K via blockIdx.z)
// ---------------------------------------------------------------------------
#define MFMA_Q(MQ, NH)                                                        \
  do {                                                                        \
    __builtin_amdgcn_s_setprio(1);                                            \
    _Pragma("unroll") for (int m_ = 0; m_ < 4; ++m_)                          \
      _Pragma("unroll") for (int n_ = 0; n_ < 2; ++n_)                        \
        _Pragma("unroll") for (int ks_ = 0; ks_ < 2; ++ks_)                   \
          acc[MQ * 4 + m_][NH * 2 + n_] =                                     \
            __builtin_amdgcn_mfma_f32_16x16x32_bf16(                          \
              aF[m_][ks_], (NH ? b1F : b0F)[n_][ks_],                         \
              acc[MQ * 4 + m_][NH * 2 + n_], 0, 0, 0);                        \
    __builtin_amdgcn_s_setprio(0);                                            \
  } while (0)

template<int MODE>
__global__ __launch_bounds__(512, 2) void gemm256(
    const u16* __restrict__ A, int lda, const u16* __restrict__ BT, int ldb,
    int K, u16* __restrict__ o1, const float* __restrict__ bias,
    u16* __restrict__ pout)
{
  __shared__ alignas(16) u16 lds[2][2][256 * 64];   // [buf][A|B][row*64+col]
  const int tid = threadIdx.x, lane = tid & 63, w = tid >> 6;
  const int wm = w >> 2, wn = w & 3;
  const int fr = lane & 15, g = lane >> 4;
  const int gx = gridDim.x, nwg = gx * gridDim.y;
  int lid = blockIdx.y * gx + blockIdx.x;
  lid = (lid & 7) * (nwg >> 3) + (lid >> 3);        // XCD swizzle (nwg%8==0)
  const int col0 = (lid % gx) * 256, row0 = (lid / gx) * 256;
  const int koff = (MODE == 3) ? blockIdx.z * 1024 : 0;
  if constexpr (MODE == 3) pout += (size_t)blockIdx.z * (4096 * 1024);

  const int srow = w * 16 + (lane >> 3);
  const int scol8 = (lane & 7) ^ ((lane >> 3) & 7); // pre-swizzled source col
  const u16* Ab = A  + (size_t)(row0 + srow) * lda + koff + scol8 * 8;
  const u16* Bb = BT + (size_t)(col0 + srow) * ldb + koff + scol8 * 8;
  const int sdst = (w * 16) * 64 + lane * 8;

  const int x7 = fr & 7;                            // read-side xor (row&7)
  const int rA = wm * 128 + fr;
  const int rB = wn * 64 + fr;

  f32x4 acc[8][4] = {};
  s16x8 aF[4][2], b0F[2][2], b1F[2][2];
  const int nkt = K >> 6;

  auto stA = [&](int buf, int half, int kt) {
    #pragma unroll
    for (int g2 = 0; g2 < 2; ++g2)
      gload16(Ab + (size_t)(half * 128 + g2 * 8) * lda + kt * 64,
              &lds[buf][0][(half * 128 + g2 * 8) * 64 + sdst]);
  };
  auto stB = [&](int buf, int half, int kt) {
    #pragma unroll
    for (int g2 = 0; g2 < 2; ++g2)
      gload16(Bb + (size_t)(half * 128 + g2 * 8) * ldb + kt * 64,
              &lds[buf][1][(half * 128 + g2 * 8) * 64 + sdst]);
  };
  auto rdA = [&](int buf, int mq) {
    #pragma unroll
    for (int m = 0; m < 4; ++m)
      #pragma unroll
      for (int ks = 0; ks < 2; ++ks)
        aF[m][ks] = *(const s16x8*)
          &lds[buf][0][(rA + mq * 64 + m * 16) * 64 + ((ks * 4 + g) ^ x7) * 8];
  };
  auto rdB0 = [&](int buf) {
    #pragma unroll
    for (int n = 0; n < 2; ++n)
      #pragma unroll
      for (int ks = 0; ks < 2; ++ks)
        b0F[n][ks] = *(const s16x8*)
          &lds[buf][1][(rB + n * 16) * 64 + ((ks * 4 + g) ^ x7) * 8];
  };
  auto rdB1 = [&](int buf) {
    #pragma unroll
    for (int n = 0; n < 2; ++n)
      #pragma unroll
      for (int ks = 0; ks < 2; ++ks)
        b1F[n][ks] = *(const s16x8*)
          &lds[buf][1][(rB + (n + 2) * 16) * 64 + ((ks * 4 + g) ^ x7) * 8];
  };

  stA(0, 0, 0); stA(0, 1, 0); stB(0, 0, 0); stB(0, 1, 0);
  stA(1, 0, 1); stA(1, 1, 1); stB(1, 0, 1); stB(1, 1, 1);
  WAITB(8);

  const int niter = nkt >> 1;
  for (int i = 0; i < niter; ++i) {
    #pragma unroll
    for (int half = 0; half < 2; ++half) {
      const int buf = half;
      const int skt = 2 * i + 2 + half;
      const bool st = (skt < nkt);
      rdA(buf, 0); rdB0(buf);
      BAR();
      MFMA_Q(0, 0);
      BAR();
      rdB1(buf);
      if (st) stB(buf, 0, skt);
      BAR();
      MFMA_Q(0, 1);
      BAR();
      rdA(buf, 1);
      if (st) stA(buf, 0, skt);
      BAR();
      MFMA_Q(1, 0);
      BAR();
      if (st) { stA(buf, 1, skt); stB(buf, 1, skt); }
      BAR();
      MFMA_Q(1, 1);
      WAITB(6);
    }
  }

  #pragma unroll
  for (int m8 = 0; m8 < 8; ++m8) {
    const int rbase = row0 + wm * 128 + m8 * 16 + g * 4;
    #pragma unroll
    for (int n4 = 0; n4 < 4; ++n4) {
      const int col = col0 + wn * 64 + n4 * 16 + fr;
      if constexpr (MODE == 1) {
        const float bb = bias[col];
        #pragma unroll
        for (int j = 0; j < 4; ++j)
          o1[(size_t)(rbase + j) * 4096 + col] =
            f2bf(fmaxf(acc[m8][n4][j] + bb, 0.0f));
      } else {
        #pragma unroll
        for (int j = 0; j < 4; ++j)
          pout[(size_t)(rbase + j) * 1024 + col] = f2bf(acc[m8][n4][j]);
      }
    }
  }
}

// ---------------------------------------------------------------------------
// FF2 reduce: out = sum_z partial[z] + b2 + e2.  f32x4 per thread.
// ---------------------------------------------------------------------------
__global__ __launch_bounds__(256) void ff2_reduce(
    const u16* __restrict__ pbuf, const float* __restrict__ e2,
    const float* __restrict__ b2, float* __restrict__ out)
{
  const int i4 = blockIdx.x * 256 + threadIdx.x;
  const int row = i4 >> 8, c4 = i4 & 255;
  float4 a = ((const float4*)e2)[i4];
  const float4 bb = ((const float4*)b2)[c4];
  a.x += bb.x; a.y += bb.y; a.z += bb.z; a.w += bb.w;
  #pragma unroll
  for (int z = 0; z < 4; ++z) {
    const ushort4 p = *(const ushort4*)
      &pbuf[(size_t)z * (4096 * 1024) + (size_t)row * 1024 + c4 * 4];
    a.x += bf2f(p.x); a.y += bf2f(p.y); a.z += bf2f(p.z); a.w += bf2f(p.w);
  }
  ((float4*)out)[i4] = a;
}

// ---------------------------------------------------------------------------
// MFMA flash attention: 32-row waves + split-depth ring.
// Block = (bh, 128-row q-block); 4 waves x 32 q-rows (2 x 16-row subtiles).
// K/V fragments -> REGISTERS once per chunk, reused across both subtiles
// (halves LDS b128 reads vs 16-row waves). K ring depth-3, V depth-2.
// Steady-state waits (2 gloads per stage): WAITB(4) -> K(t) landed;
// WAITB(2) -> V(t) landed (tail iters use WAITB(0) exactly).
// p_sm: ONE buffer per wave, reused across subtiles (pf read to regs before
// overwrite; wave-local in-order DS). NO-MAX softmax (q pre-scaled by
// d^-0.5*log2e): P = exp2(S), denom = plain sum.
// ---------------------------------------------------------------------------
__global__ __launch_bounds__(256, 3) void attn_mfma(
    const u16* __restrict__ q, const u16* __restrict__ kfragG,
    const u16* __restrict__ vfragG, const float* __restrict__ embds,
    float* __restrict__ e2)
{
  __shared__ alignas(16) u16 kbuf[3][4096];
  __shared__ alignas(16) u16 vbuf[2][4096];
  __shared__ alignas(16) u16 p_sm[4][16][72];
  const int tid = threadIdx.x, lane = tid & 63, wave = tid >> 6;
  const int bh = blockIdx.x & 31;           // same-bh blocks -> same XCD (L2)
  const int qb = 15 - (blockIdx.x >> 5);    // long q-blocks first
  const int q0 = qb * 128 + wave * 32;      // this wave's 32-row q-tile
  const int b = bh >> 4, h = bh & 15;
  const int fr = lane & 15, g = lane >> 4;

  s16x8 qf[2][2];
  #pragma unroll
  for (int u = 0; u < 2; ++u) {
    const u16* qp = q + ((size_t)bh * 2048 + q0 + u * 16 + fr) * 64 + g * 8;
    qf[u][0] = *(const s16x8*)(qp);
    qf[u][1] = *(const s16x8*)(qp + 32);
  }

  f32x4 o_acc[2][4] = {};
  float lacc[2][4] = {};

  const size_t fragbase = (size_t)bh * 131072;
  const int nch = qb * 2 + 2;

  auto stage_k = [&](int sel, int c) {      // wave stages K-pairs 2w, 2w+1
    const size_t cb = fragbase + (size_t)c * 4096;
    gload16(kfragG + cb + (wave * 2 + 0) * 512 + lane * 8, &kbuf[sel][(wave * 2 + 0) * 512]);
    gload16(kfragG + cb + (wave * 2 + 1) * 512 + lane * 8, &kbuf[sel][(wave * 2 + 1) * 512]);
  };
  auto stage_v = [&](int sel, int c) {      // wave stages V-pairs 2w, 2w+1
    const size_t cb = fragbase + (size_t)c * 4096;
    gload16(vfragG + cb + (wave * 2 + 0) * 512 + lane * 8, &vbuf[sel][(wave * 2 + 0) * 512]);
    gload16(vfragG + cb + (wave * 2 + 1) * 512 + lane * 8, &vbuf[sel][(wave * 2 + 1) * 512]);
  };

  // prologue: K0, K1, V0 in flight (issue order matters for counted waits)
  stage_k(0, 0);
  if (nch > 1) stage_k(1, 1);
  stage_v(0, 0);

  int kc = 0;                               // kbuf slot of chunk t (t % 3)
  for (int t = 0; t < nch; ++t) {
    WAITB(4);                               // K(t) landed (<= {K(t+1),V(t)} outstanding)
    const int kn2 = (kc >= 1) ? kc - 1 : kc + 2;   // (t+2) % 3
    if (t + 2 < nch) stage_k(kn2, t + 2);

    // ---- K chunk -> registers (once; reused for both subtiles) ----
    s16x8 kf[8];
    #pragma unroll
    for (int p = 0; p < 8; ++p)
      kf[p] = *(const s16x8*)&kbuf[kc][p * 512 + lane * 8];

    // ---- per-subtile QK^T + exp2 + P->LDS->pf regs ----
    const int s0 = t * 64;
    s16x8 pfr[2][2];
    #pragma unroll
    for (int u = 0; u < 2; ++u) {
      const int q0u = q0 + u * 16;
      f32x4 sacc[4] = {};
      #pragma unroll
      for (int n = 0; n < 4; ++n) {
        sacc[n] = __builtin_amdgcn_mfma_f32_16x16x32_bf16(qf[u][0], kf[n * 2 + 0], sacc[n], 0, 0, 0);
        sacc[n] = __builtin_amdgcn_mfma_f32_16x16x32_bf16(qf[u][1], kf[n * 2 + 1], sacc[n], 0, 0, 0);
      }
      if (s0 + 63 > q0u) {                  // causal mask (diagonal chunks)
        #pragma unroll
        for (int n = 0; n < 4; ++n) {
          const int s = s0 + n * 16 + fr;
          #pragma unroll
          for (int j = 0; j < 4; ++j)
            if (s > q0u + g * 4 + j) sacc[n][j] = -1e30f;
        }
      }
      #pragma unroll
      for (int n = 0; n < 4; ++n)
        #pragma unroll
        for (int j = 0; j < 4; ++j) {
          const float pe = __builtin_amdgcn_exp2f(sacc[n][j]);
          lacc[u][j] += pe;
          p_sm[wave][g * 4 + j][n * 16 + fr] = f2bf(pe);
        }
      // read pf into regs BEFORE next subtile overwrites p_sm (in-order DS)
      pfr[u][0] = *(const s16x8*)&p_sm[wave][fr][g * 8];
      pfr[u][1] = *(const s16x8*)&p_sm[wave][fr][32 + g * 8];
    }

    // ---- V(t) landed; tail iterations need full drain ----
    if (t + 2 < nch) { WAITB(2); } else { WAITB(0); }
    if (t + 1 < nch) stage_v((t + 1) & 1, t + 1);

    // ---- V chunk -> registers; PV for both subtiles ----
    const int vc = t & 1;
    s16x8 vf[8];
    #pragma unroll
    for (int p = 0; p < 8; ++p)
      vf[p] = *(const s16x8*)&vbuf[vc][p * 512 + lane * 8];
    #pragma unroll
    for (int u = 0; u < 2; ++u)
      #pragma unroll
      for (int n = 0; n < 4; ++n) {
        o_acc[u][n] = __builtin_amdgcn_mfma_f32_16x16x32_bf16(pfr[u][0], vf[n * 2 + 0], o_acc[u][n], 0, 0, 0);
        o_acc[u][n] = __builtin_amdgcn_mfma_f32_16x16x32_bf16(pfr[u][1], vf[n * 2 + 1], o_acc[u][n], 0, 0, 0);
      }
    kc = (kc == 2) ? 0 : kc + 1;
  }

  // ---- final denominator reduce (within 16-lane groups) ----
  #pragma unroll
  for (int u = 0; u < 2; ++u)
    #pragma unroll
    for (int j = 0; j < 4; ++j) {
      #pragma unroll
      for (int mm = 1; mm < 16; mm <<= 1) lacc[u][j] += __shfl_xor(lacc[u][j], mm);
    }

  // ---- epilogue: e2 = embds + O/l ----
  #pragma unroll
  for (int u = 0; u < 2; ++u)
    #pragma unroll
    for (int n = 0; n < 4; ++n) {
      #pragma unroll
      for (int j = 0; j < 4; ++j) {
        const int t = q0 + u * 16 + g * 4 + j;
        const size_t oi = ((size_t)b * 2048 + t) * 1024 + (size_t)h * 64 + n * 16 + fr;
        e2[oi] = embds[oi] + o_acc[u][n][j] / lacc[u][j];
      }
    }
}

// ---------------------------------------------------------------------------
extern "C" void kernel_launch(void* const* d_in, const int* in_sizes, int n_in,
                              void* d_out, int out_size, void* d_ws, size_t ws_size,
                              hipStream_t stream) {
  const float* embds = (const float*)d_in[0];
  const float* Wq    = (const float*)d_in[1];
  const float* Wk    = (const float*)d_in[2];
  const float* Wv    = (const float*)d_in[3];
  const float* ln1g  = (const float*)d_in[4];
  const float* ln1b  = (const float*)d_in[5];
  const float* ln2g  = (const float*)d_in[6];
  const float* ln2b  = (const float*)d_in[7];
  const float* W1    = (const float*)d_in[8];
  const float* b1    = (const float*)d_in[9];
  const float* W2    = (const float*)d_in[10];
  const float* b2    = (const float*)d_in[11];
  float* out = (float*)d_out;

  char* ws = (char*)d_ws;
  u16*   xln   = (u16*)(ws);                          // 8 MB  [4096][1024] bf16
  u16*   pbuf  = (u16*)(ws);                          // 32 MB FF2 partials (dead overlap OK)
  u16*   wqkvT = (u16*)(ws + (8ull  << 20));          // 6 MB
  u16*   qbuf  = (u16*)(ws + (14ull << 20));          // 8 MB
  u16*   kfrag = (u16*)(ws + (22ull << 20));          // 8 MB
  u16*   vfrag = (u16*)(ws + (30ull << 20));          // 8 MB
  float* e2    = (float*)(ws + (38ull << 20));        // 16 MB
  u16*   ybuf  = (u16*)(ws + (54ull << 20));          // 8 MB
  u16*   w1T   = (u16*)(ws + (62ull << 20));          // 8 MB  [4096][1024]
  u16*   w2T   = (u16*)(ws + (70ull << 20));          // 8 MB  [1024][4096]
  u16*   hid   = (u16*)(ws + (78ull << 20));          // 32 MB [4096][4096]

  transpose_qkv<<<dim3(1, 16, 48), 256, 0, stream>>>(Wq, Wk, Wv, wqkvT);
  transpose_pack<<<dim3(64, 16, 1), 256, 0, stream>>>(W1, w1T, 1024, 4096);
  transpose_pack<<<dim3(16, 64, 1), 256, 0, stream>>>(W2, w2T, 4096, 1024);
  ln_kernel<<<4096, 256, 0, stream>>>(embds, ln1g, ln1b, xln);
  gemm128<0, 2><<<dim3(24, 32), 256, 0, stream>>>(xln, wqkvT, 1024,
      qbuf, kfrag, vfrag, nullptr, nullptr, nullptr, nullptr);
  attn_mfma<<<512, 256, 0, stream>>>(qbuf, kfrag, vfrag, embds, e2);
  ln_kernel<<<4096, 256, 0, stream>>>(e2, ln2g, ln2b, ybuf);
  gemm256<1><<<dim3(16, 16), 512, 0, stream>>>(ybuf, 1024, w1T, 1024, 1024,
      hid, b1, nullptr);
  gemm256<3><<<dim3(4, 16, 4), 512, 0, stream>>>(hid, 4096, w2T, 4096, 1024,
      nullptr, nullptr, pbuf);
  ff2_reduce<<<4096, 256, 0, stream>>>(pbuf, e2, b2, out);
}

// Round 17
// 182.859 us; speedup vs baseline: 1.0738x; 1.0738x over previous
//
#include <hip/hip_runtime.h>

using s16x8 = __attribute__((ext_vector_type(8))) short;
using f32x4 = __attribute__((ext_vector_type(4))) float;
typedef unsigned int   u32;
typedef unsigned short u16;

__device__ __forceinline__ u16 f2bf(float f) {
  u32 u = __float_as_uint(f);
  u += 0x7fffu + ((u >> 16) & 1u);   // round-to-nearest-even
  return (u16)(u >> 16);
}
__device__ __forceinline__ float bf2f(u16 s) {
  return __uint_as_float(((u32)s) << 16);
}

typedef __attribute__((address_space(1))) const unsigned int g_u32;
typedef __attribute__((address_space(3))) unsigned int l_u32;
__device__ __forceinline__ void gload16(const void* g, void* l) {
  __builtin_amdgcn_global_load_lds((g_u32*)g, (l_u32*)l, 16, 0, 0);
}

// counted waitcnt + raw barrier (no compiler vmcnt(0) drain)
#define WAITB(N) asm volatile("s_waitcnt vmcnt(" #N ")\ns_barrier" ::: "memory")
#define BAR()    asm volatile("s_barrier" ::: "memory")

// K fragment-order address (u16 index): [bh][chunk][pair(n,h)][lane][8]
__device__ __forceinline__ size_t kfrag_addr(int bh, int t, int e) {
  const int pair = (((t >> 4) & 3) << 1) + (e >> 5);
  const int slot = ((e >> 3) & 3) * 16 + (t & 15);
  return ((((size_t)bh * 32 + (t >> 6)) * 8 + pair) * 64 + slot) * 8 + (e & 7);
}
// V fragment-order address: subtile n = e>>4, k-dim = token
__device__ __forceinline__ size_t vfrag_addr(int bh, int t, int e) {
  const int pair = (((e >> 4) & 3) << 1) + ((t >> 5) & 1);
  const int slot = ((t >> 3) & 3) * 16 + (e & 15);
  return ((((size_t)bh * 32 + (t >> 6)) * 8 + pair) * 64 + slot) * 8 + (t & 7);
}

// ---------------------------------------------------------------------------
// Fused weight pack (verified in R11 bench): all transposes in one launch.
// 64x64 tiles. idx<768: Wq/Wk/Wv heads; <1792: W1; else W2.
// ---------------------------------------------------------------------------
__global__ __launch_bounds__(256) void pack_all(
    const float* __restrict__ Wq, const float* __restrict__ Wk,
    const float* __restrict__ Wv, const float* __restrict__ W1,
    const float* __restrict__ W2, u16* __restrict__ wqkvT,
    u16* __restrict__ w1T, u16* __restrict__ w2T)
{
  __shared__ u16 tile[64][66];
  const int idx = blockIdx.x, tid = threadIdx.x;
  const float* src; u16* dst; int R, C, r0, c0;
  if (idx < 768) {                       // qkv: z = idx>>4 (0..47), ry = idx&15
    const int z = idx >> 4, ry = idx & 15;
    const int sel = z >> 4, head = z & 15;
    src = ((sel == 0) ? Wq : (sel == 1) ? Wk : Wv) + (size_t)head * 65536;
    dst = wqkvT + ((size_t)sel << 20) + (size_t)head * 65536;
    R = 1024; C = 64; r0 = ry * 64; c0 = 0;
  } else if (idx < 1792) {               // W1 [1024][4096] -> w1T [4096][1024]
    const int i = idx - 768;
    src = W1; dst = w1T; R = 1024; C = 4096;
    r0 = (i >> 6) * 64; c0 = (i & 63) * 64;
  } else {                               // W2 [4096][1024] -> w2T [1024][4096]
    const int i = idx - 1792;
    src = W2; dst = w2T; R = 4096; C = 1024;
    r0 = (i >> 4) * 64; c0 = (i & 15) * 64;
  }
  const int rr = tid >> 6, cc = tid & 63;
  #pragma unroll
  for (int i = 0; i < 16; ++i)
    tile[i * 4 + rr][cc] = f2bf(src[(size_t)(r0 + i * 4 + rr) * C + c0 + cc]);
  __syncthreads();
  #pragma unroll
  for (int i = 0; i < 16; ++i)
    dst[(size_t)(c0 + i * 4 + rr) * R + r0 + cc] = tile[cc][i * 4 + rr];
}

// ---------------------------------------------------------------------------
// LayerNorm: f32 [4096][1024] -> bf16 [4096][1024]. One block per row.
// ---------------------------------------------------------------------------
__global__ __launch_bounds__(256) void ln_kernel(
    const float* __restrict__ x, const float* __restrict__ g,
    const float* __restrict__ be, u16* __restrict__ out)
{
  const int row = blockIdx.x, tid = threadIdx.x;
  const int lane = tid & 63, wave = tid >> 6;
  const float4 v = ((const float4*)(x + (size_t)row * 1024))[tid];
  float s  = v.x + v.y + v.z + v.w;
  float sq = v.x * v.x + v.y * v.y + v.z * v.z + v.w * v.w;
  #pragma unroll
  for (int m = 1; m < 64; m <<= 1) { s += __shfl_xor(s, m); sq += __shfl_xor(sq, m); }
  __shared__ float rs[4], rq[4];
  if (lane == 0) { rs[wave] = s; rq[wave] = sq; }
  __syncthreads();
  s  = rs[0] + rs[1] + rs[2] + rs[3];
  sq = rq[0] + rq[1] + rq[2] + rq[3];
  const float mean = s * (1.0f / 1024.0f);
  const float var  = sq * (1.0f / 1024.0f) - mean * mean;
  const float rstd = rsqrtf(var + 1e-5f);
  const int c = tid * 4;
  const float4 gv = ((const float4*)g)[tid];
  const float4 bv = ((const float4*)be)[tid];
  ushort4 o;
  o.x = f2bf((v.x - mean) * rstd * gv.x + bv.x);
  o.y = f2bf((v.y - mean) * rstd * gv.y + bv.y);
  o.z = f2bf((v.z - mean) * rstd * gv.z + bv.z);
  o.w = f2bf((v.w - mean) * rstd * gv.w + bv.w);
  *(ushort4*)&out[(size_t)row * 1024 + c] = o;
}

// ---------------------------------------------------------------------------
// bf16 MFMA GEMM: C = A[M][K]*BT[N][K]^T. Tile (64*MR)x128, BK=32, 4 waves,
// depth-3 LDS ring, counted-vmcnt raw barrier, swizzled staging, XCD swizzle.
// MODE 0: QKV epilogue (q scaled LOG2E/32; K,V -> fragment-order layouts)
// ---------------------------------------------------------------------------
template<int MODE, int MR>
__global__ __launch_bounds__(256) void gemm128(
    const u16* __restrict__ A, const u16* __restrict__ BT, int K,
    u16* __restrict__ o0q, u16* __restrict__ o0k, u16* __restrict__ o0v,
    u16* __restrict__ o1, const float* __restrict__ bias,
    float* __restrict__ o2, const float* __restrict__ resid)
{
  constexpr int BM = 64 * MR;
  __shared__ alignas(16) u16 As[3][BM * 32];
  __shared__ alignas(16) u16 Bs[3][128 * 32];
  const int tid = threadIdx.x, lane = tid & 63, wave = tid >> 6;
  const int wr = wave >> 1, wc = wave & 1;
  const int gx = gridDim.x;
  const int nwg = gx * gridDim.y;
  int lid = blockIdx.y * gx + blockIdx.x;
  lid = (lid & 7) * (nwg >> 3) + (lid >> 3);
  const int row0 = (lid / gx) * BM, col0 = (lid % gx) * 128;
  const int fr = lane & 15, g = lane >> 4;
  const int swz = (g ^ ((fr >> 1) & 3)) * 8;

  const int sr = wave * 16 + (lane >> 2);
  const int sc = ((lane & 3) ^ ((lane >> 3) & 3)) * 8;
  const u16* Ap0 = A  + (size_t)(row0 + sr) * K + sc;
  const u16* Ap1 = A  + (size_t)(row0 + 64 + sr) * K + sc;
  const u16* Bp0 = BT + (size_t)(col0 + sr) * K + sc;
  const u16* Bp1 = BT + (size_t)(col0 + 64 + sr) * K + sc;

  f32x4 acc[2 * MR][4] = {};

  auto stage = [&](int sel, int k0) {
    gload16(Ap0 + k0, &As[sel][wave * 512]);
    if constexpr (MR == 2) gload16(Ap1 + k0, &As[sel][(4 + wave) * 512]);
    gload16(Bp0 + k0, &Bs[sel][wave * 512]);
    gload16(Bp1 + k0, &Bs[sel][(4 + wave) * 512]);
  };
  auto compute = [&](int sel) {
    s16x8 af[2 * MR], bfr[4];
    #pragma unroll
    for (int m = 0; m < 2 * MR; ++m)
      af[m] = *(const s16x8*)&As[sel][(wr * (32 * MR) + m * 16 + fr) * 32 + swz];
    #pragma unroll
    for (int n = 0; n < 4; ++n)
      bfr[n] = *(const s16x8*)&Bs[sel][(wc * 64 + n * 16 + fr) * 32 + swz];
    #pragma unroll
    for (int m = 0; m < 2 * MR; ++m)
      #pragma unroll
      for (int n = 0; n < 4; ++n)
        acc[m][n] = __builtin_amdgcn_mfma_f32_16x16x32_bf16(af[m], bfr[n], acc[m][n], 0, 0, 0);
  };

  const int nsteps = K / 32;
  stage(0, 0);
  stage(1, 32);
  int cur = 0;
  for (int t = 0; t < nsteps - 1; ++t) {
    if constexpr (MR == 2) WAITB(4); else WAITB(3);
    const int nxt = (cur == 2) ? 0 : cur + 1;
    const int nn  = (nxt == 2) ? 0 : nxt + 1;
    if (t + 2 < nsteps) stage(nn, (t + 2) * 32);
    compute(cur);
    cur = nxt;
  }
  WAITB(0);
  compute(cur);

  const float QSCALE = 0.03125f * 1.4426950408889634f;  // d^-0.5 * log2(e)
  #pragma unroll
  for (int m = 0; m < 2 * MR; ++m) {
    const int rbase = row0 + wr * (32 * MR) + m * 16 + g * 4;
    #pragma unroll
    for (int n = 0; n < 4; ++n) {
      const int col = col0 + wc * 64 + n * 16 + fr;
      if constexpr (MODE == 0) {
        const int ww = col >> 10, h = (col >> 6) & 15, e = col & 63;
        const int b = rbase >> 11, t0 = rbase & 2047;
        const int bh = b * 16 + h;
        if (ww == 0) {
          #pragma unroll
          for (int j = 0; j < 4; ++j)
            o0q[((size_t)bh * 2048 + (t0 + j)) * 64 + e] = f2bf(acc[m][n][j] * QSCALE);
        } else if (ww == 1) {
          #pragma unroll
          for (int j = 0; j < 4; ++j)
            o0k[kfrag_addr(bh, t0 + j, e)] = f2bf(acc[m][n][j]);
        } else {
          ushort4 pk;
          pk.x = f2bf(acc[m][n][0]); pk.y = f2bf(acc[m][n][1]);
          pk.z = f2bf(acc[m][n][2]); pk.w = f2bf(acc[m][n][3]);
          *(ushort4*)&o0v[vfrag_addr(bh, t0, e)] = pk;
        }
      } else if constexpr (MODE == 1) {
        const float bb = bias[col];
        #pragma unroll
        for (int j = 0; j < 4; ++j) {
          float v = fmaxf(acc[m][n][j] + bb, 0.0f);
          o1[(size_t)(rbase + j) * 4096 + col] = f2bf(v);
        }
      } else {
        const float bb = bias[col];
        #pragma unroll
        for (int j = 0; j < 4; ++j) {
          const size_t ix = (size_t)(rbase + j) * 1024 + col;
          o2[ix] = acc[m][n][j] + bb + resid[ix];
        }
      }
    }
  }
}

// ---------------------------------------------------------------------------
// 8-phase 256x256 GEMM (m201-style). BK=64, 512 thr, 8 waves (2M x 4N),
// per-wave 128x64 out, 128KB LDS double-buffer, involution swizzle,
// raw barriers, vmcnt(6) at K-tile boundaries only, setprio, XCD swizzle.
// MODE 1: +bias+ReLU -> bf16 [.][4096]
// MODE 3: raw bf16 partial [.][1024] (split-K via blockIdx.z)
// ---------------------------------------------------------------------------
#define MFMA_Q(MQ, NH)                                                        \
  do {                                                                        \
    __builtin_amdgcn_s_setprio(1);                                            \
    _Pragma("unroll") for (int m_ = 0; m_ < 4; ++m_)                          \
      _Pragma("unroll") for (int n_ = 0; n_ < 2; ++n_)                        \
        _Pragma("unroll") for (int ks_ = 0; ks_ < 2; ++ks_)                   \
          acc[MQ * 4 + m_][NH * 2 + n_] =                                     \
            __builtin_amdgcn_mfma_f32_16x16x32_bf16(                          \
              aF[m_][ks_], (NH ? b1F : b0F)[n_][ks_],                         \
              acc[MQ * 4 + m_][NH * 2 + n_], 0, 0, 0);                        \
    __builtin_amdgcn_s_setprio(0);                                            \
  } while (0)

template<int MODE>
__global__ __launch_bounds__(512, 2) void gemm256(
    const u16* __restrict__ A, int lda, const u16* __restrict__ BT, int ldb,
    int K, u16* __restrict__ o1, const float* __restrict__ bias,
    u16* __restrict__ pout)
{
  __shared__ alignas(16) u16 lds[2][2][256 * 64];   // [buf][A|B][row*64+col]
  const int tid = threadIdx.x, lane = tid & 63, w = tid >> 6;
  const int wm = w >> 2, wn = w & 3;
  const int fr = lane & 15, g = lane >> 4;
  const int gx = gridDim.x, nwg = gx * gridDim.y;
  int lid = blockIdx.y * gx + blockIdx.x;
  lid = (lid & 7) * (nwg >> 3) + (lid >> 3);        // XCD swizzle (nwg%8==0)
  const int col0 = (lid % gx) * 256, row0 = (lid / gx) * 256;
  const int koff = (MODE == 3) ? blockIdx.z * 1024 : 0;
  if constexpr (MODE == 3) pout += (size_t)blockIdx.z * (4096 * 1024);

  const int srow = w * 16 + (lane >> 3);
  const int scol8 = (lane & 7) ^ ((lane >> 3) & 7); // pre-swizzled source col
  const u16* Ab = A  + (size_t)(row0 + srow) * lda + koff + scol8 * 8;
  const u16* Bb = BT + (size_t)(col0 + srow) * ldb + koff + scol8 * 8;
  const int sdst = (w * 16) * 64 + lane * 8;

  const int x7 = fr & 7;                            // read-side xor (row&7)
  const int rA = wm * 128 + fr;
  const int rB = wn * 64 + fr;

  f32x4 acc[8][4] = {};
  s16x8 aF[4][2], b0F[2][2], b1F[2][2];
  const int nkt = K >> 6;

  auto stA = [&](int buf, int half, int kt) {
    #pragma unroll
    for (int g2 = 0; g2 < 2; ++g2)
      gload16(Ab + (size_t)(half * 128 + g2 * 8) * lda + kt * 64,
              &lds[buf][0][(half * 128 + g2 * 8) * 64 + sdst]);
  };
  auto stB = [&](int buf, int half, int kt) {
    #pragma unroll
    for (int g2 = 0; g2 < 2; ++g2)
      gload16(Bb + (size_t)(half * 128 + g2 * 8) * ldb + kt * 64,
              &lds[buf][1][(half * 128 + g2 * 8) * 64 + sdst]);
  };
  auto rdA = [&](int buf, int mq) {
    #pragma unroll
    for (int m = 0; m < 4; ++m)
      #pragma unroll
      for (int ks = 0; ks < 2; ++ks)
        aF[m][ks] = *(const s16x8*)
          &lds[buf][0][(rA + mq * 64 + m * 16) * 64 + ((ks * 4 + g) ^ x7) * 8];
  };
  auto rdB0 = [&](int buf) {
    #pragma unroll
    for (int n = 0; n < 2; ++n)
      #pragma unroll
      for (int ks = 0; ks < 2; ++ks)
        b0F[n][ks] = *(const s16x8*)
          &lds[buf][1][(rB + n * 16) * 64 + ((ks * 4 + g) ^ x7) * 8];
  };
  auto rdB1 = [&](int buf) {
    #pragma unroll
    for (int n = 0; n < 2; ++n)
      #pragma unroll
      for (int ks = 0; ks < 2; ++ks)
        b1F[n][ks] = *(const s16x8*)
          &lds[buf][1][(rB + (n + 2) * 16) * 64 + ((ks * 4 + g) ^ x7) * 8];
  };

  stA(0, 0, 0); stA(0, 1, 0); stB(0, 0, 0); stB(0, 1, 0);
  stA(1, 0, 1); stA(1, 1, 1); stB(1, 0, 1); stB(1, 1, 1);
  WAITB(8);

  const int niter = nkt >> 1;
  for (int i = 0; i < niter; ++i) {
    #pragma unroll
    for (int half = 0; half < 2; ++half) {
      const int buf = half;
      const int skt = 2 * i + 2 + half;
      const bool st = (skt < nkt);
      rdA(buf, 0); rdB0(buf);
      BAR();
      MFMA_Q(0, 0);
      BAR();
      rdB1(buf);
      if (st) stB(buf, 0, skt);
      BAR();
      MFMA_Q(0, 1);
      BAR();
      rdA(buf, 1);
      if (st) stA(buf, 0, skt);
      BAR();
      MFMA_Q(1, 0);
      BAR();
      if (st) { stA(buf, 1, skt); stB(buf, 1, skt); }
      BAR();
      MFMA_Q(1, 1);
      WAITB(6);
    }
  }

  #pragma unroll
  for (int m8 = 0; m8 < 8; ++m8) {
    const int rbase = row0 + wm * 128 + m8 * 16 + g * 4;
    #pragma unroll
    for (int n4 = 0; n4 < 4; ++n4) {
      const int col = col0 + wn * 64 + n4 * 16 + fr;
      if constexpr (MODE == 1) {
        const float bb = bias[col];
        #pragma unroll
        for (int j = 0; j < 4; ++j)
          o1[(size_t)(rbase + j) * 4096 + col] =
            f2bf(fmaxf(acc[m8][n4][j] + bb, 0.0f));
      } else {
        #pragma unroll
        for (int j = 0; j < 4; ++j)
          pout[(size_t)(rbase + j) * 1024 + col] = f2bf(acc[m8][n4][j]);
      }
    }
  }
}

// ---------------------------------------------------------------------------
// FF2 reduce: out = sum_z partial[z] + b2 + e2.  f32x4 per thread.
// ---------------------------------------------------------------------------
__global__ __launch_bounds__(256) void ff2_reduce(
    const u16* __restrict__ pbuf, const float* __restrict__ e2,
    const float* __restrict__ b2, float* __restrict__ out)
{
  const int i4 = blockIdx.x * 256 + threadIdx.x;
  const int row = i4 >> 8, c4 = i4 & 255;
  float4 a = ((const float4*)e2)[i4];
  const float4 bb = ((const float4*)b2)[c4];
  a.x += bb.x; a.y += bb.y; a.z += bb.z; a.w += bb.w;
  #pragma unroll
  for (int z = 0; z < 4; ++z) {
    const ushort4 p = *(const ushort4*)
      &pbuf[(size_t)z * (4096 * 1024) + (size_t)row * 1024 + c4 * 4];
    a.x += bf2f(p.x); a.y += bf2f(p.y); a.z += bf2f(p.z); a.w += bf2f(p.w);
  }
  ((float4*)out)[i4] = a;
}

// ---------------------------------------------------------------------------
// MFMA flash attention (R15 structure + tail-safe V wait).
// Block = (bh, 128-row q-block); 8 waves x 16 q-rows.
// K ring depth-3 (staged 2 chunks ahead), V ring depth-2 (1 chunk ahead).
// Steady waits: WAITB(2) -> K(t) landed; WAITB(1) -> V(t) landed.
// Tail (no K(t+2) staged): V wait must be WAITB(0) (in-order vmcnt).
// NO-MAX softmax (q pre-scaled by d^-0.5*log2e): P = exp2(S), denom = sum.
// ---------------------------------------------------------------------------
__global__ __launch_bounds__(512, 6) void attn_mfma(
    const u16* __restrict__ q, const u16* __restrict__ kfragG,
    const u16* __restrict__ vfragG, const float* __restrict__ embds,
    float* __restrict__ e2)
{
  __shared__ alignas(16) u16 kbuf[3][4096];
  __shared__ alignas(16) u16 vbuf[2][4096];
  __shared__ alignas(16) u16 p_sm[8][16][72];
  const int tid = threadIdx.x, lane = tid & 63, wave = tid >> 6;
  const int bh = blockIdx.x & 31;           // same-bh blocks -> same XCD (L2)
  const int qb = 15 - (blockIdx.x >> 5);    // long q-blocks first
  const int q0 = qb * 128 + wave * 16;
  const int b = bh >> 4, h = bh & 15;
  const int fr = lane & 15, g = lane >> 4;

  const u16* qp = q + ((size_t)bh * 2048 + q0 + fr) * 64 + g * 8;
  const s16x8 qf0 = *(const s16x8*)(qp);
  const s16x8 qf1 = *(const s16x8*)(qp + 32);

  f32x4 o_acc[4] = {};
  float lacc[4] = {};

  const size_t fragbase = (size_t)bh * 131072;
  const int nch = qb * 2 + 2;

  auto stage_k = [&](int sel, int c) {      // wave stages K-pair `wave`
    gload16(kfragG + fragbase + (size_t)c * 4096 + wave * 512 + lane * 8,
            &kbuf[sel][wave * 512]);
  };
  auto stage_v = [&](int sel, int c) {      // wave stages V-pair `wave`
    gload16(vfragG + fragbase + (size_t)c * 4096 + wave * 512 + lane * 8,
            &vbuf[sel][wave * 512]);
  };

  // prologue: K0,K1 and V0 in flight (issue order: K0, K1, V0)
  stage_k(0, 0);
  if (nch > 1) stage_k(1, 1);
  stage_v(0, 0);

  int kc = 0;                               // kbuf index of chunk t (t % 3)
  for (int t = 0; t < nch; ++t) {
    WAITB(2);                               // K(t) landed (all waves)
    const int kn2 = (kc >= 1) ? kc - 1 : kc + 2;   // (t+2) % 3
    if (t + 2 < nch) stage_k(kn2, t + 2);

    // ---- QK^T: S[16 q][64 s] (units of log2e) ----
    const int s0 = t * 64;
    f32x4 sacc[4] = {};
    #pragma unroll
    for (int n = 0; n < 4; ++n) {
      const s16x8 kf0 = *(const s16x8*)&kbuf[kc][(n * 2 + 0) * 512 + lane * 8];
      const s16x8 kf1 = *(const s16x8*)&kbuf[kc][(n * 2 + 1) * 512 + lane * 8];
      sacc[n] = __builtin_amdgcn_mfma_f32_16x16x32_bf16(qf0, kf0, sacc[n], 0, 0, 0);
      sacc[n] = __builtin_amdgcn_mfma_f32_16x16x32_bf16(qf1, kf1, sacc[n], 0, 0, 0);
    }
    // ---- causal mask (diagonal chunks only) ----
    if (s0 + 63 > q0) {
      #pragma unroll
      for (int n = 0; n < 4; ++n) {
        const int s = s0 + n * 16 + fr;
        #pragma unroll
        for (int j = 0; j < 4; ++j)
          if (s > q0 + g * 4 + j) sacc[n][j] = -1e30f;
      }
    }
    // ---- P = exp2(S); denom per-lane; P -> LDS (wave-local) ----
    #pragma unroll
    for (int n = 0; n < 4; ++n)
      #pragma unroll
      for (int j = 0; j < 4; ++j) {
        const float pe = __builtin_amdgcn_exp2f(sacc[n][j]);
        lacc[j] += pe;
        p_sm[wave][g * 4 + j][n * 16 + fr] = f2bf(pe);
      }

    // ---- V(t) landed; tail iterations need full drain ----
    if (t + 2 < nch) { WAITB(1); } else { WAITB(0); }
    if (t + 1 < nch) stage_v((t + 1) & 1, t + 1);

    // ---- PV: O += P * V ----
    const int vc = t & 1;
    const s16x8 pf0 = *(const s16x8*)&p_sm[wave][fr][g * 8];
    const s16x8 pf1 = *(const s16x8*)&p_sm[wave][fr][32 + g * 8];
    #pragma unroll
    for (int n = 0; n < 4; ++n) {
      const s16x8 vf0 = *(const s16x8*)&vbuf[vc][(n * 2 + 0) * 512 + lane * 8];
      const s16x8 vf1 = *(const s16x8*)&vbuf[vc][(n * 2 + 1) * 512 + lane * 8];
      o_acc[n] = __builtin_amdgcn_mfma_f32_16x16x32_bf16(pf0, vf0, o_acc[n], 0, 0, 0);
      o_acc[n] = __builtin_amdgcn_mfma_f32_16x16x32_bf16(pf1, vf1, o_acc[n], 0, 0, 0);
    }
    kc = (kc == 2) ? 0 : kc + 1;
  }

  // ---- final denominator reduce (within 16-lane groups) ----
  #pragma unroll
  for (int j = 0; j < 4; ++j) {
    #pragma unroll
    for (int mm = 1; mm < 16; mm <<= 1) lacc[j] += __shfl_xor(lacc[j], mm);
  }
  // ---- epilogue: e2 = embds + O/l ----
  #pragma unroll
  for (int n = 0; n < 4; ++n) {
    #pragma unroll
    for (int j = 0; j < 4; ++j) {
      const int t = q0 + g * 4 + j;
      const size_t oi = ((size_t)b * 2048 + t) * 1024 + (size_t)h * 64 + n * 16 + fr;
      e2[oi] = embds[oi] + o_acc[n][j] / lacc[j];
    }
  }
}

// ---------------------------------------------------------------------------
extern "C" void kernel_launch(void* const* d_in, const int* in_sizes, int n_in,
                              void* d_out, int out_size, void* d_ws, size_t ws_size,
                              hipStream_t stream) {
  const float* embds = (const float*)d_in[0];
  const float* Wq    = (const float*)d_in[1];
  const float* Wk    = (const float*)d_in[2];
  const float* Wv    = (const float*)d_in[3];
  const float* ln1g  = (const float*)d_in[4];
  const float* ln1b  = (const float*)d_in[5];
  const float* ln2g  = (const float*)d_in[6];
  const float* ln2b  = (const float*)d_in[7];
  const float* W1    = (const float*)d_in[8];
  const float* b1    = (const float*)d_in[9];
  const float* W2    = (const float*)d_in[10];
  const float* b2    = (const float*)d_in[11];
  float* out = (float*)d_out;

  char* ws = (char*)d_ws;
  u16*   xln   = (u16*)(ws);                          // 8 MB  [4096][1024] bf16
  u16*   pbuf  = (u16*)(ws);                          // 32 MB FF2 partials (dead overlap OK)
  u16*   wqkvT = (u16*)(ws + (8ull  << 20));          // 6 MB
  u16*   qbuf  = (u16*)(ws + (14ull << 20));          // 8 MB
  u16*   kfrag = (u16*)(ws + (22ull << 20));          // 8 MB
  u16*   vfrag = (u16*)(ws + (30ull << 20));          // 8 MB
  float* e2    = (float*)(ws + (38ull << 20));        // 16 MB
  u16*   ybuf  = (u16*)(ws + (54ull << 20));          // 8 MB
  u16*   w1T   = (u16*)(ws + (62ull << 20));          // 8 MB  [4096][1024]
  u16*   w2T   = (u16*)(ws + (70ull << 20));          // 8 MB  [1024][4096]
  u16*   hid   = (u16*)(ws + (78ull << 20));          // 32 MB [4096][4096]

  pack_all<<<2816, 256, 0, stream>>>(Wq, Wk, Wv, W1, W2, wqkvT, w1T, w2T);
  ln_kernel<<<4096, 256, 0, stream>>>(embds, ln1g, ln1b, xln);
  gemm128<0, 2><<<dim3(24, 32), 256, 0, stream>>>(xln, wqkvT, 1024,
      qbuf, kfrag, vfrag, nullptr, nullptr, nullptr, nullptr);
  attn_mfma<<<512, 512, 0, stream>>>(qbuf, kfrag, vfrag, embds, e2);
  ln_kernel<<<4096, 256, 0, stream>>>(e2, ln2g, ln2b, ybuf);
  gemm256<1><<<dim3(16, 16), 512, 0, stream>>>(ybuf, 1024, w1T, 1024, 1024,
      hid, b1, nullptr);
  gemm256<3><<<dim3(4, 16, 4), 512, 0, stream>>>(hid, 4096, w2T, 4096, 1024,
      nullptr, nullptr, pbuf);
  ff2_reduce<<<4096, 256, 0, stream>>>(pbuf, e2, b2, out);
}